// Round 9
// baseline (887.234 us; speedup 1.0000x reference)
//
#include <hip/hip_runtime.h>

// GRU (reset_after) fused, MI355X gfx950. B=8192, T=256, F=64, H=50.
// Occupancy-first variant: M=8 rows/block, 1024 blocks x 256 thr -> 4
// blocks/CU = 16 waves/CU (4/SIMD), quadrupling independent recurrence
// chains per SIMD to hide the per-step ds_read->MFMA->trans latency chain.
// A-frag rows 8-15 are zero-pad. Gate-blocked B cols (lane owns z/r/h of
// unit u=16w+(l&15)); exp2 scale-folded gates with biases in MFMA C-init;
// 1 raw barrier/step (no vmcnt drain: x prefetch stays in flight).

typedef __attribute__((ext_vector_type(8))) short s16x8;
typedef __attribute__((ext_vector_type(2))) float f32x2;
typedef __attribute__((ext_vector_type(4))) float f32x4;

#define TS 256

__device__ __forceinline__ unsigned short f2bf(float f) {
  unsigned int v = __builtin_bit_cast(unsigned int, f);
  v += 0x7FFFu + ((v >> 16) & 1u);
  return (unsigned short)(v >> 16);
}
__device__ __forceinline__ unsigned int cvtpk(float a, float b) {
  unsigned int r;
  asm("v_cvt_pk_bf16_f32 %0, %1, %2" : "=v"(r) : "v"(a), "v"(b));
  return r;
}
__device__ __forceinline__ float rcpf(float a) {
  return __builtin_amdgcn_rcpf(a);
}

// LDS-visibility barrier WITHOUT vmcnt drain.
#define RAWBAR()                                                \
  do {                                                          \
    asm volatile("s_waitcnt lgkmcnt(0)" ::: "memory");          \
    __builtin_amdgcn_sched_barrier(0);                          \
    __builtin_amdgcn_s_barrier();                               \
  } while (0)

__global__ __launch_bounds__(256, 4) void gru_fused(
    const float* __restrict__ x,  const float* __restrict__ W,
    const float* __restrict__ U,  const float* __restrict__ b,
    const float* __restrict__ Wd, const float* __restrict__ bdp,
    float* __restrict__ out)
{
  __shared__ __align__(16) unsigned short xbuf[2][2][512]; // [par][kchunk]
  __shared__ __align__(16) unsigned short hbuf[2][2][512];
  __shared__ float red[4][8];

  const int tid = threadIdx.x;
  const int l   = tid & 63;
  const int w   = tid >> 6;
  const int lhi = l >> 4, llo = l & 15;
  const int row0 = blockIdx.x << 3;        // 8 rows per block
  const int u = (w << 4) + llo;            // hidden unit (pad >= 50)

  // zero xbuf+hbuf fully: pad rows (8-15) stay zero forever; h(t=-1)=0.
  ((unsigned long long*)xbuf)[tid]       = 0ULL;
  ((unsigned long long*)xbuf)[tid + 256] = 0ULL;
  ((unsigned long long*)hbuf)[tid]       = 0ULL;
  ((unsigned long long*)hbuf)[tid + 256] = 0ULL;

  const float sZR = -1.44269504088896f;    // -log2(e)
  const float sH  =  2.88539008177793f;    //  2*log2(e)
  float bzS = 0.f, brS = 0.f, bh0S = 0.f, bh1S = 0.f;
  if (u < 50) {
    bzS  = sZR * (b[u]      + b[150 + u]);
    brS  = sZR * (b[50 + u] + b[200 + u]);
    bh0S = sH * b[100 + u];
    bh1S = sH * b[250 + u];
  }

  // B fragments, gate-blocked cols (g: 0=z,1=r,2=h -> src col g*50+u),
  // pre-scaled so gate pre-activations are exp2 arguments directly.
  s16x8 breg[3][4];
  #pragma unroll
  for (int g = 0; g < 3; ++g) {
    const float scg = (g < 2) ? sZR : sH;
    #pragma unroll
    for (int kc = 0; kc < 4; ++kc) {
      s16x8 f;
      #pragma unroll
      for (int i = 0; i < 8; ++i) {
        const int k = kc * 32 + lhi * 8 + i;
        float v = 0.f;
        if (u < 50 && k < 114)
          v = (k < 64) ? W[k * 150 + g * 50 + u]
                       : U[(k - 64) * 150 + g * 50 + u];
        f[i] = (short)f2bf(v * scg);
      }
      breg[g][kc] = f;
    }
  }

  // x staging: 8 rows x 64 k = 512 f32/step; thread covers 2 consecutive k.
  const int sc   = tid >> 7;               // k-chunk 0/1
  const int rem  = tid & 127;
  const int srow = rem >> 4;               // 0..7
  const int koff = (rem & 15) << 1;        // 0,2,..,30 within chunk
  const float* xp = x + (long)(row0 + srow) * (TS * 64) + sc * 32 + koff;
  const int sidx = ((((koff >> 3) * 16 + srow) << 3) + (koff & 7)) >> 1;
  unsigned int* const xd0 = (unsigned int*)&xbuf[0][sc][0] + sidx;
  unsigned int* const xd1 = (unsigned int*)&xbuf[1][sc][0] + sidx;

  // h-store base: unit u at k-slot u -> chunk u>>5, lane ((u&31)>>3)*16+row.
  unsigned short* const hst =
      &hbuf[0][u >> 5][((((u & 31) >> 3) * 16 + lhi * 4) << 3) + (u & 7)];

  // prologue: stage x(0) -> par0; ring x(1..4) in regs
  {
    const f32x2 t0 = *(const f32x2*)xp;
    *xd0 = cvtpk(t0[0], t0[1]);
  }
  f32x2 R0 = *(const f32x2*)(xp + 1 * 64);
  f32x2 R1 = *(const f32x2*)(xp + 2 * 64);
  f32x2 R2 = *(const f32x2*)(xp + 3 * 64);
  f32x2 R3 = *(const f32x2*)(xp + 4 * 64);
  __syncthreads();

  float h0 = 0.f, h1 = 0.f, h2 = 0.f, h3 = 0.f;

// Step T (computes h(T) for rows 0-7): read par T&1 (x(T), h(T-1));
// stage CUR=x(T+1) -> par (T&1)^1; reload CUR = x(T+5); gates on lanes
// lhi<2 only (rows 8-15 are pad); h(T) -> hbuf[(T&1)^1]. One raw barrier.
#define STEP(T, CUR)                                                           \
  {                                                                            \
    const int PAR = (T) & 1;                                                   \
    const s16x8 a0 = *(const s16x8*)&xbuf[PAR][0][l * 8];                      \
    const s16x8 a1 = *(const s16x8*)&xbuf[PAR][1][l * 8];                      \
    const s16x8 a2 = *(const s16x8*)&hbuf[PAR][0][l * 8];                      \
    const s16x8 a3 = *(const s16x8*)&hbuf[PAR][1][l * 8];                      \
    f32x4 g0 = {bzS, bzS, bzS, bzS};                                           \
    g0 = __builtin_amdgcn_mfma_f32_16x16x32_bf16(a0, breg[0][0], g0, 0,0,0);   \
    g0 = __builtin_amdgcn_mfma_f32_16x16x32_bf16(a1, breg[0][1], g0, 0,0,0);   \
    g0 = __builtin_amdgcn_mfma_f32_16x16x32_bf16(a2, breg[0][2], g0, 0,0,0);   \
    g0 = __builtin_amdgcn_mfma_f32_16x16x32_bf16(a3, breg[0][3], g0, 0,0,0);   \
    f32x4 g1 = {brS, brS, brS, brS};                                           \
    g1 = __builtin_amdgcn_mfma_f32_16x16x32_bf16(a0, breg[1][0], g1, 0,0,0);   \
    g1 = __builtin_amdgcn_mfma_f32_16x16x32_bf16(a1, breg[1][1], g1, 0,0,0);   \
    g1 = __builtin_amdgcn_mfma_f32_16x16x32_bf16(a2, breg[1][2], g1, 0,0,0);   \
    g1 = __builtin_amdgcn_mfma_f32_16x16x32_bf16(a3, breg[1][3], g1, 0,0,0);   \
    f32x4 gx = {bh0S, bh0S, bh0S, bh0S};                                       \
    gx = __builtin_amdgcn_mfma_f32_16x16x32_bf16(a0, breg[2][0], gx, 0,0,0);   \
    gx = __builtin_amdgcn_mfma_f32_16x16x32_bf16(a1, breg[2][1], gx, 0,0,0);   \
    f32x4 gh = {bh1S, bh1S, bh1S, bh1S};                                       \
    gh = __builtin_amdgcn_mfma_f32_16x16x32_bf16(a2, breg[2][2], gh, 0,0,0);   \
    gh = __builtin_amdgcn_mfma_f32_16x16x32_bf16(a3, breg[2][3], gh, 0,0,0);   \
    *(PAR ? xd0 : xd1) = cvtpk(CUR[0], CUR[1]);                                \
    {                                                                          \
      const int tl = ((T) + 5 > TS - 1) ? (TS - 1) : ((T) + 5);                \
      CUR = *(const f32x2*)(xp + (long)tl * 64);                               \
    }                                                                          \
    if (lhi < 2) {                                                             \
      _Pragma("unroll")                                                        \
      for (int r = 0; r < 4; ++r) {                                            \
        float hv = (r == 0) ? h0 : (r == 1) ? h1 : (r == 2) ? h2 : h3;         \
        const float z  = rcpf(1.f + exp2f(g0[r]));                             \
        const float rr = rcpf(1.f + exp2f(g1[r]));                             \
        const float q  = rcpf(1.f + exp2f(fmaf(rr, gh[r], gx[r])));            \
        const float hh = fmaf(-2.f, q, 1.f);                                   \
        hv = fmaf(z, hv - hh, hh);                                             \
        if (r == 0) h0 = hv; else if (r == 1) h1 = hv;                         \
        else if (r == 2) h2 = hv; else h3 = hv;                                \
        hst[((PAR) ^ 1) * 1024 + r * 8] = (unsigned short)cvtpk(hv, 0.f);      \
      }                                                                        \
    }                                                                          \
    RAWBAR();                                                                  \
  }

  for (int t = 0; t < TS; t += 4) {
    STEP(t + 0, R0)
    STEP(t + 1, R1)
    STEP(t + 2, R2)
    STEP(t + 3, R3)
  }
#undef STEP

  // epilogue: out[row] = sum_u h[row][u]*Wd[u] + bd (rows 0-7)
  const float Wdv = (u < 50) ? Wd[u] : 0.f;
  float p0 = h0 * Wdv, p1 = h1 * Wdv, p2 = h2 * Wdv, p3 = h3 * Wdv;
  #pragma unroll
  for (int m = 1; m < 16; m <<= 1) {
    p0 += __shfl_xor(p0, m);
    p1 += __shfl_xor(p1, m);
    p2 += __shfl_xor(p2, m);
    p3 += __shfl_xor(p3, m);
  }
  if (llo == 0 && lhi < 2) {
    red[w][lhi * 4 + 0] = p0;
    red[w][lhi * 4 + 1] = p1;
    red[w][lhi * 4 + 2] = p2;
    red[w][lhi * 4 + 3] = p3;
  }
  __syncthreads();
  if (tid < 8)
    out[row0 + tid] =
        red[0][tid] + red[1][tid] + red[2][tid] + red[3][tid] + bdp[0];
}

extern "C" void kernel_launch(void* const* d_in, const int* in_sizes, int n_in,
                              void* d_out, int out_size, void* d_ws, size_t ws_size,
                              hipStream_t stream) {
  const float* x   = (const float*)d_in[0];
  const float* W   = (const float*)d_in[1];
  const float* U   = (const float*)d_in[2];
  const float* b   = (const float*)d_in[3];
  const float* Wd  = (const float*)d_in[4];
  const float* bdp = (const float*)d_in[5];
  float* out = (float*)d_out;
  gru_fused<<<dim3(1024), dim3(256), 0, stream>>>(x, W, U, b, Wd, bdp, out);
}